// Round 1
// baseline (419.357 us; speedup 1.0000x reference)
//
#include <hip/hip_runtime.h>

#define SEQ 2048
#define BATCH 2
#define DM 1024
#define NH 16
#define DK 64
#define BH (BATCH*NH)

typedef __attribute__((ext_vector_type(8))) short bf16x8;
typedef __attribute__((ext_vector_type(4))) float f32x4;

__device__ __forceinline__ ushort f2bf(float f) {
  union { float f; unsigned u; } v; v.f = f;
  unsigned r = (v.u + 0x7fffu + ((v.u >> 16) & 1u)) >> 16;
  return (ushort)r;
}
__device__ __forceinline__ float bf2f(ushort h) {
  union { unsigned u; float f; } v; v.u = ((unsigned)h) << 16;
  return v.f;
}

// ---------------- cast fp32 -> bf16, vectorized ----------------
__global__ void k_cast(const float* __restrict__ in, ushort* __restrict__ out, int n4) {
  int i = blockIdx.x * blockDim.x + threadIdx.x;
  int st = gridDim.x * blockDim.x;
  for (; i < n4; i += st) {
    float4 v = reinterpret_cast<const float4*>(in)[i];
    ushort4 o;
    o.x = f2bf(v.x); o.y = f2bf(v.y); o.z = f2bf(v.z); o.w = f2bf(v.w);
    reinterpret_cast<ushort4*>(out)[i] = o;
  }
}

// ---------------- RoPE cos/sin table: [SEQ][32] pairs ----------------
__global__ void k_rope_tab(float* __restrict__ tab) {
  int id = blockIdx.x * blockDim.x + threadIdx.x;
  if (id >= SEQ * 32) return;
  int s = id >> 5, i = id & 31;
  float inv = powf(10000.f, -(float)i / 32.f);
  float ang = (float)s * inv;
  float sn, cs;
  sincosf(ang, &sn, &cs);
  tab[id * 2] = cs;
  tab[id * 2 + 1] = sn;
}

// ---------------- RoPE apply + head-transpose: Y[b,s,h*64+d] -> T[bh,s,d] ----------------
__global__ void k_rope(const ushort* __restrict__ Y, ushort* __restrict__ T,
                       const float* __restrict__ tab) {
  int idx = blockIdx.x * blockDim.x + threadIdx.x;
  if (idx >= BH * SEQ * 32) return;
  int i = idx & 31;
  int s = (idx >> 5) & (SEQ - 1);
  int bh = idx >> 16;            // SEQ*32 == 1<<16
  int b = bh >> 4, h = bh & 15;
  ushort2 x = *(const ushort2*)(Y + (size_t)(b * SEQ + s) * DM + h * 64 + 2 * i);
  float xe = bf2f(x.x), xo = bf2f(x.y);
  float cs = tab[((s << 5) + i) * 2], sn = tab[((s << 5) + i) * 2 + 1];
  ushort2 o;
  o.x = f2bf(xe * cs - xo * sn);
  o.y = f2bf(xe * sn + xo * cs);
  *(ushort2*)(T + (size_t)(bh * SEQ + s) * 64 + 2 * i) = o;
}

// ---------------- V transpose: Y[b,s,h*64+d] -> VT[bh, d, s] ----------------
__global__ __launch_bounds__(256) void k_tr_v(const ushort* __restrict__ Y,
                                              ushort* __restrict__ VT) {
  __shared__ ushort tile[64][65];
  const int st = blockIdx.x, bh = blockIdx.y;
  const int b = bh >> 4, h = bh & 15;
  const int d = threadIdx.x & 63, s4 = threadIdx.x >> 6;
#pragma unroll
  for (int p = 0; p < 16; ++p) {
    int sl = p * 4 + s4;
    tile[d][sl] = Y[(size_t)(b * SEQ + st * 64 + sl) * DM + h * 64 + d];
  }
  __syncthreads();
  const int sl = threadIdx.x & 63, d4 = threadIdx.x >> 6;
#pragma unroll
  for (int p = 0; p < 16; ++p) {
    int dl = p * 4 + d4;
    VT[(size_t)bh * DK * SEQ + (size_t)dl * SEQ + st * 64 + sl] = tile[dl][sl];
  }
}

// ---------------- async global->LDS 16B ----------------
__device__ __forceinline__ void gll16(const void* g, void* l) {
  __builtin_amdgcn_global_load_lds((const __attribute__((address_space(1))) void*)g,
                                   (__attribute__((address_space(3))) void*)l, 16, 0, 0);
}

// ---------------- GEMM: C[M,N] = A[M,K] * Bw[N,K]^T  (bf16 in, OUT out) ----------------
template <typename OUT>
__global__ __launch_bounds__(256) void k_gemm_bt(const ushort* __restrict__ A,
                                                 const ushort* __restrict__ Bw,
                                                 OUT* __restrict__ C, int M, int N, int K) {
  __shared__ ushort As[128 * 32];
  __shared__ ushort Bs[128 * 32];
  const int tid = threadIdx.x;
  const int w = tid >> 6, lane = tid & 63;
  const int l15 = lane & 15, l4 = lane >> 4;
  const int m0 = blockIdx.y * 128, n0 = blockIdx.x * 128;
  const int wr = w >> 1, wc = w & 1;
  const int lrow = lane >> 2, lcol = (lane & 3) * 8;
  f32x4 acc[4][4] = {};
  for (int kk = 0; kk < K; kk += 32) {
    __syncthreads();
    gll16(A + (size_t)(m0 + w * 16 + lrow) * K + kk + lcol, (void*)(As + w * 512));
    gll16(A + (size_t)(m0 + 64 + w * 16 + lrow) * K + kk + lcol, (void*)(As + 2048 + w * 512));
    gll16(Bw + (size_t)(n0 + w * 16 + lrow) * K + kk + lcol, (void*)(Bs + w * 512));
    gll16(Bw + (size_t)(n0 + 64 + w * 16 + lrow) * K + kk + lcol, (void*)(Bs + 2048 + w * 512));
    __syncthreads();
    bf16x8 af[4], bfr[4];
#pragma unroll
    for (int i = 0; i < 4; ++i)
      af[i] = *(const bf16x8*)(As + (wr * 64 + i * 16 + l15) * 32 + l4 * 8);
#pragma unroll
    for (int i = 0; i < 4; ++i)
      bfr[i] = *(const bf16x8*)(Bs + (wc * 64 + i * 16 + l15) * 32 + l4 * 8);
#pragma unroll
    for (int mi = 0; mi < 4; ++mi)
#pragma unroll
      for (int ni = 0; ni < 4; ++ni)
        acc[mi][ni] = __builtin_amdgcn_mfma_f32_16x16x32_bf16(af[mi], bfr[ni], acc[mi][ni], 0, 0, 0);
  }
#pragma unroll
  for (int mi = 0; mi < 4; ++mi)
#pragma unroll
    for (int ni = 0; ni < 4; ++ni)
#pragma unroll
      for (int r = 0; r < 4; ++r) {
        int row = m0 + wr * 64 + mi * 16 + l4 * 4 + r;
        int col = n0 + wc * 64 + ni * 16 + l15;
        float v = acc[mi][ni][r];
        if constexpr (sizeof(OUT) == 2)
          C[(size_t)row * N + col] = (OUT)f2bf(v);
        else
          C[(size_t)row * N + col] = (OUT)v;
      }
}

// ---------------- causal flash attention ----------------
// qT,kT: [bh, s, 64]   vT: [bh, 64, s]   AO: [b, s, h*64+d]
__global__ __launch_bounds__(256) void k_flash(const ushort* __restrict__ qT,
                                               const ushort* __restrict__ kT,
                                               const ushort* __restrict__ vT,
                                               ushort* __restrict__ AO) {
  __shared__ short Plds[4 * 1024];  // 4 waves x 2048B (16x64 bf16, swizzled)
  const int qt = blockIdx.x, bh = blockIdx.y;
  const int tid = threadIdx.x, w = tid >> 6, lane = tid & 63;
  const int l15 = lane & 15, l4 = lane >> 4;
  const size_t hb = (size_t)bh * SEQ * DK;
  const int qrow0 = qt * 64 + w * 16;
  bf16x8 qa0 = *(const bf16x8*)(qT + hb + (size_t)(qrow0 + l15) * 64 + l4 * 8);
  bf16x8 qa1 = *(const bf16x8*)(qT + hb + (size_t)(qrow0 + l15) * 64 + 32 + l4 * 8);
  f32x4 acc[4] = {};
  float mrun[4], lrun[4];
#pragma unroll
  for (int r = 0; r < 4; ++r) { mrun[r] = -INFINITY; lrun[r] = 0.f; }
  char* myP = (char*)Plds + w * 2048;
  for (int kt = 0; kt <= qt; ++kt) {
    const ushort* kb = kT + hb + kt * 64 * 64;
    f32x4 sfr[4];
#pragma unroll
    for (int nf = 0; nf < 4; ++nf) {
      bf16x8 k0 = *(const bf16x8*)(kb + (nf * 16 + l15) * 64 + l4 * 8);
      bf16x8 k1 = *(const bf16x8*)(kb + (nf * 16 + l15) * 64 + 32 + l4 * 8);
      f32x4 z = {0.f, 0.f, 0.f, 0.f};
      z = __builtin_amdgcn_mfma_f32_16x16x32_bf16(qa0, k0, z, 0, 0, 0);
      z = __builtin_amdgcn_mfma_f32_16x16x32_bf16(qa1, k1, z, 0, 0, 0);
      sfr[nf] = z;
    }
    float p[4][4];
#pragma unroll
    for (int nf = 0; nf < 4; ++nf)
#pragma unroll
      for (int r = 0; r < 4; ++r) {
        float sc = sfr[nf][r] * 0.125f;
        if (kt == qt && (nf * 16 + l15) > (w * 16 + l4 * 4 + r)) sc = -INFINITY;
        p[nf][r] = sc;
      }
    float so[4];
#pragma unroll
    for (int r = 0; r < 4; ++r) {
      float mx = fmaxf(fmaxf(p[0][r], p[1][r]), fmaxf(p[2][r], p[3][r]));
      mx = fmaxf(mx, __shfl_xor(mx, 1));
      mx = fmaxf(mx, __shfl_xor(mx, 2));
      mx = fmaxf(mx, __shfl_xor(mx, 4));
      mx = fmaxf(mx, __shfl_xor(mx, 8));
      float mn = fmaxf(mrun[r], mx);
      so[r] = __expf(mrun[r] - mn);
      float rs = 0.f;
#pragma unroll
      for (int nf = 0; nf < 4; ++nf) {
        float e = __expf(p[nf][r] - mn);
        p[nf][r] = e;
        rs += e;
      }
      rs += __shfl_xor(rs, 1); rs += __shfl_xor(rs, 2);
      rs += __shfl_xor(rs, 4); rs += __shfl_xor(rs, 8);
      lrun[r] = lrun[r] * so[r] + rs;
      mrun[r] = mn;
    }
#pragma unroll
    for (int df = 0; df < 4; ++df)
#pragma unroll
      for (int r = 0; r < 4; ++r) acc[df][r] *= so[r];
    // P (C-layout) -> LDS, XOR-swizzled
#pragma unroll
    for (int nf = 0; nf < 4; ++nf)
#pragma unroll
      for (int r = 0; r < 4; ++r) {
        int m = l4 * 4 + r, n = nf * 16 + l15;
        *(short*)(myP + ((m * 128 + n * 2) ^ ((m & 7) << 4))) = (short)f2bf(p[nf][r]);
      }
    __syncthreads();
    bf16x8 pa0 = *(const bf16x8*)(myP + ((l15 * 128 + l4 * 16) ^ ((l15 & 7) << 4)));
    bf16x8 pa1 = *(const bf16x8*)(myP + ((l15 * 128 + 64 + l4 * 16) ^ ((l15 & 7) << 4)));
    const ushort* vb = vT + (size_t)bh * DK * SEQ + kt * 64;
#pragma unroll
    for (int df = 0; df < 4; ++df) {
      bf16x8 v0 = *(const bf16x8*)(vb + (size_t)(df * 16 + l15) * SEQ + l4 * 8);
      bf16x8 v1 = *(const bf16x8*)(vb + (size_t)(df * 16 + l15) * SEQ + 32 + l4 * 8);
      acc[df] = __builtin_amdgcn_mfma_f32_16x16x32_bf16(pa0, v0, acc[df], 0, 0, 0);
      acc[df] = __builtin_amdgcn_mfma_f32_16x16x32_bf16(pa1, v1, acc[df], 0, 0, 0);
    }
    __syncthreads();
  }
  const int b = bh >> 4, h = bh & 15;
#pragma unroll
  for (int r = 0; r < 4; ++r) {
    float inv = 1.f / lrun[r];
    int qrow = qrow0 + l4 * 4 + r;
#pragma unroll
    for (int df = 0; df < 4; ++df) {
      AO[(size_t)(b * SEQ + qrow) * DM + h * 64 + df * 16 + l15] = f2bf(acc[df][r] * inv);
    }
  }
}

extern "C" void kernel_launch(void* const* d_in, const int* in_sizes, int n_in,
                              void* d_out, int out_size, void* d_ws, size_t ws_size,
                              hipStream_t stream) {
  const float* Q = (const float*)d_in[0];
  const float* K = (const float*)d_in[1];
  const float* V = (const float*)d_in[2];
  const float* wq = (const float*)d_in[3];
  const float* wk = (const float*)d_in[4];
  const float* wv = (const float*)d_in[5];
  const float* wo = (const float*)d_in[6];
  float* out = (float*)d_out;
  char* ws = (char*)d_ws;

  ushort* XQ = (ushort*)(ws + 0);          // 8 MB each
  ushort* XK = (ushort*)(ws + 8388608);
  ushort* XV = (ushort*)(ws + 16777216);
  ushort* WQ = (ushort*)(ws + 25165824);   // 2 MB each
  ushort* WK = (ushort*)(ws + 27262976);
  ushort* WV = (ushort*)(ws + 29360128);
  ushort* WO = (ushort*)(ws + 31457280);
  ushort* YQ = (ushort*)(ws + 33554432);   // 8 MB each
  ushort* YK = (ushort*)(ws + 41943040);
  ushort* YV = (ushort*)(ws + 50331648);
  float* TAB = (float*)(ws + 58720256);    // 512 KB
  // aliases (stream-ordered reuse)
  ushort* qTt = XQ;
  ushort* kTt = XK;
  ushort* vTt = XV;
  ushort* AO = YQ;

  const int NX4 = BATCH * SEQ * DM / 4;
  const int NW4 = DM * DM / 4;
  k_cast<<<2048, 256, 0, stream>>>(Q, XQ, NX4);
  k_cast<<<2048, 256, 0, stream>>>(K, XK, NX4);
  k_cast<<<2048, 256, 0, stream>>>(V, XV, NX4);
  k_cast<<<1024, 256, 0, stream>>>(wq, WQ, NW4);
  k_cast<<<1024, 256, 0, stream>>>(wk, WK, NW4);
  k_cast<<<1024, 256, 0, stream>>>(wv, WV, NW4);
  k_cast<<<1024, 256, 0, stream>>>(wo, WO, NW4);
  k_rope_tab<<<(SEQ * 32) / 256, 256, 0, stream>>>(TAB);

  dim3 gg(DM / 128, (BATCH * SEQ) / 128);
  k_gemm_bt<ushort><<<gg, 256, 0, stream>>>(XQ, WQ, YQ, BATCH * SEQ, DM, DM);
  k_gemm_bt<ushort><<<gg, 256, 0, stream>>>(XK, WK, YK, BATCH * SEQ, DM, DM);
  k_gemm_bt<ushort><<<gg, 256, 0, stream>>>(XV, WV, YV, BATCH * SEQ, DM, DM);

  k_rope<<<(BH * SEQ * 32) / 256, 256, 0, stream>>>(YQ, qTt, TAB);
  k_rope<<<(BH * SEQ * 32) / 256, 256, 0, stream>>>(YK, kTt, TAB);
  k_tr_v<<<dim3(SEQ / 64, BH), 256, 0, stream>>>(YV, vTt);

  k_flash<<<dim3(SEQ / 64, BH), 256, 0, stream>>>(qTt, kTt, vTt, AO);

  k_gemm_bt<float><<<gg, 256, 0, stream>>>(AO, WO, out, BATCH * SEQ, DM, DM);
}

// Round 2
// 297.463 us; speedup vs baseline: 1.4098x; 1.4098x over previous
//
#include <hip/hip_runtime.h>

#define SEQ 2048
#define BATCH 2
#define DM 1024
#define NH 16
#define DK 64
#define BH (BATCH*NH)

typedef __attribute__((ext_vector_type(8))) short bf16x8;
typedef __attribute__((ext_vector_type(4))) float f32x4;

__device__ __forceinline__ ushort f2bf(float f) {
  union { float f; unsigned u; } v; v.f = f;
  unsigned r = (v.u + 0x7fffu + ((v.u >> 16) & 1u)) >> 16;
  return (ushort)r;
}
__device__ __forceinline__ float bf2f(ushort h) {
  union { unsigned u; float f; } v; v.u = ((unsigned)h) << 16;
  return v.f;
}

// ---------------- cast fp32 -> bf16, vectorized ----------------
__global__ void k_cast(const float* __restrict__ in, ushort* __restrict__ out, int n4) {
  int i = blockIdx.x * blockDim.x + threadIdx.x;
  int st = gridDim.x * blockDim.x;
  for (; i < n4; i += st) {
    float4 v = reinterpret_cast<const float4*>(in)[i];
    ushort4 o;
    o.x = f2bf(v.x); o.y = f2bf(v.y); o.z = f2bf(v.z); o.w = f2bf(v.w);
    reinterpret_cast<ushort4*>(out)[i] = o;
  }
}

// ---------------- RoPE cos/sin table: [SEQ][32] pairs ----------------
__global__ void k_rope_tab(float* __restrict__ tab) {
  int id = blockIdx.x * blockDim.x + threadIdx.x;
  if (id >= SEQ * 32) return;
  int s = id >> 5, i = id & 31;
  float inv = powf(10000.f, -(float)i / 32.f);
  float ang = (float)s * inv;
  float sn, cs;
  sincosf(ang, &sn, &cs);
  tab[id * 2] = cs;
  tab[id * 2 + 1] = sn;
}

// ---------------- RoPE apply + head-transpose: Y[b,s,h*64+d] -> T[bh,s,d] ----------------
__global__ void k_rope(const ushort* __restrict__ Y, ushort* __restrict__ T,
                       const float* __restrict__ tab) {
  int idx = blockIdx.x * blockDim.x + threadIdx.x;
  if (idx >= BH * SEQ * 32) return;
  int i = idx & 31;
  int s = (idx >> 5) & (SEQ - 1);
  int bh = idx >> 16;            // SEQ*32 == 1<<16
  int b = bh >> 4, h = bh & 15;
  ushort2 x = *(const ushort2*)(Y + (size_t)(b * SEQ + s) * DM + h * 64 + 2 * i);
  float xe = bf2f(x.x), xo = bf2f(x.y);
  float cs = tab[((s << 5) + i) * 2], sn = tab[((s << 5) + i) * 2 + 1];
  ushort2 o;
  o.x = f2bf(xe * cs - xo * sn);
  o.y = f2bf(xe * sn + xo * cs);
  *(ushort2*)(T + (size_t)(bh * SEQ + s) * 64 + 2 * i) = o;
}

// ---------------- V transpose: Y[b,s,h*64+d] -> VT[bh, d, s] ----------------
__global__ __launch_bounds__(256) void k_tr_v(const ushort* __restrict__ Y,
                                              ushort* __restrict__ VT) {
  __shared__ ushort tile[64][65];
  const int st = blockIdx.x, bh = blockIdx.y;
  const int b = bh >> 4, h = bh & 15;
  const int d = threadIdx.x & 63, s4 = threadIdx.x >> 6;
#pragma unroll
  for (int p = 0; p < 16; ++p) {
    int sl = p * 4 + s4;
    tile[d][sl] = Y[(size_t)(b * SEQ + st * 64 + sl) * DM + h * 64 + d];
  }
  __syncthreads();
  const int sl = threadIdx.x & 63, d4 = threadIdx.x >> 6;
#pragma unroll
  for (int p = 0; p < 16; ++p) {
    int dl = p * 4 + d4;
    VT[(size_t)bh * DK * SEQ + (size_t)dl * SEQ + st * 64 + sl] = tile[dl][sl];
  }
}

// ---------------- async global->LDS 16B ----------------
__device__ __forceinline__ void gll16(const void* g, void* l) {
  __builtin_amdgcn_global_load_lds((const __attribute__((address_space(1))) void*)g,
                                   (__attribute__((address_space(3))) void*)l, 16, 0, 0);
}

// ---------------- GEMM: C[M,N] = A[M,K] * Bw[N,K]^T  (bf16 in, OUT out) ----------------
template <typename OUT>
__global__ __launch_bounds__(256) void k_gemm_bt(const ushort* __restrict__ A,
                                                 const ushort* __restrict__ Bw,
                                                 OUT* __restrict__ C, int M, int N, int K) {
  __shared__ ushort As[128 * 32];
  __shared__ ushort Bs[128 * 32];
  const int tid = threadIdx.x;
  const int w = tid >> 6, lane = tid & 63;
  const int l15 = lane & 15, l4 = lane >> 4;
  const int m0 = blockIdx.y * 128, n0 = blockIdx.x * 128;
  const int wr = w >> 1, wc = w & 1;
  const int lrow = lane >> 2, lcol = (lane & 3) * 8;
  f32x4 acc[4][4] = {};
  for (int kk = 0; kk < K; kk += 32) {
    __syncthreads();
    gll16(A + (size_t)(m0 + w * 16 + lrow) * K + kk + lcol, (void*)(As + w * 512));
    gll16(A + (size_t)(m0 + 64 + w * 16 + lrow) * K + kk + lcol, (void*)(As + 2048 + w * 512));
    gll16(Bw + (size_t)(n0 + w * 16 + lrow) * K + kk + lcol, (void*)(Bs + w * 512));
    gll16(Bw + (size_t)(n0 + 64 + w * 16 + lrow) * K + kk + lcol, (void*)(Bs + 2048 + w * 512));
    __syncthreads();
    bf16x8 af[4], bfr[4];
#pragma unroll
    for (int i = 0; i < 4; ++i)
      af[i] = *(const bf16x8*)(As + (wr * 64 + i * 16 + l15) * 32 + l4 * 8);
#pragma unroll
    for (int i = 0; i < 4; ++i)
      bfr[i] = *(const bf16x8*)(Bs + (wc * 64 + i * 16 + l15) * 32 + l4 * 8);
#pragma unroll
    for (int mi = 0; mi < 4; ++mi)
#pragma unroll
      for (int ni = 0; ni < 4; ++ni)
        acc[mi][ni] = __builtin_amdgcn_mfma_f32_16x16x32_bf16(af[mi], bfr[ni], acc[mi][ni], 0, 0, 0);
  }
#pragma unroll
  for (int mi = 0; mi < 4; ++mi)
#pragma unroll
    for (int ni = 0; ni < 4; ++ni)
#pragma unroll
      for (int r = 0; r < 4; ++r) {
        int row = m0 + wr * 64 + mi * 16 + l4 * 4 + r;
        int col = n0 + wc * 64 + ni * 16 + l15;
        float v = acc[mi][ni][r];
        if constexpr (sizeof(OUT) == 2)
          C[(size_t)row * N + col] = (OUT)f2bf(v);
        else
          C[(size_t)row * N + col] = (OUT)v;
      }
}

// ---------------- causal flash attention (swapped-QK^T, barrier-free) ----------------
// qT,kT: [bh, s, 64]   vT: [bh, 64, s]   AO: [b, s, h*64+d]
// Each wave owns 16 q-rows. S^T = mfma(K,Q): lane (l4,l15) holds
// S[k = nf*16 + l4*4 + r][q = l15] -> softmax reduce needs only shfl_xor 16,32.
// P written k-contiguous (ds_write_b64) into per-wave LDS, read back as MFMA
// A-fragments (XOR-swizzled rows). No __syncthreads anywhere (P is wave-private).
__global__ __launch_bounds__(256, 3) void k_flash(const ushort* __restrict__ qT,
                                                  const ushort* __restrict__ kT,
                                                  const ushort* __restrict__ vT,
                                                  ushort* __restrict__ AO) {
  __shared__ char Plds[4 * 2048];
  const int bh = blockIdx.x;
  const int qt = (SEQ / 64 - 1) - blockIdx.y;   // longest blocks dispatch first
  const int tid = threadIdx.x, w = tid >> 6, lane = tid & 63;
  const int l15 = lane & 15, l4 = lane >> 4;
  const size_t hb = (size_t)bh * SEQ * DK;
  const int qrow0 = qt * 64 + w * 16;
  // Q as B-operand fragments
  const bf16x8 qb0 = *(const bf16x8*)(qT + hb + (size_t)(qrow0 + l15) * 64 + l4 * 8);
  const bf16x8 qb1 = *(const bf16x8*)(qT + hb + (size_t)(qrow0 + l15) * 64 + 32 + l4 * 8);
  f32x4 acc[4] = {};
  float mrun = -INFINITY, lrun = 0.f;   // for q = l15 (replicated across l4 group)
  char* myP = (char*)Plds + w * 2048;
  const int swz = (l15 & 7) << 4;
  for (int kt = 0; kt <= qt; ++kt) {
    const ushort* kb = kT + hb + kt * 64 * 64;
    const ushort* vb = vT + (size_t)bh * DK * SEQ + kt * 64;
    // issue V loads first: independent, consumed at iteration end
    bf16x8 vf0[4], vf1[4];
#pragma unroll
    for (int df = 0; df < 4; ++df) {
      vf0[df] = *(const bf16x8*)(vb + (size_t)(df * 16 + l15) * SEQ + l4 * 8);
      vf1[df] = *(const bf16x8*)(vb + (size_t)(df * 16 + l15) * SEQ + 32 + l4 * 8);
    }
    // all K fragments, then MFMAs (loads overlap)
    bf16x8 ka0[4], ka1[4];
#pragma unroll
    for (int nf = 0; nf < 4; ++nf) {
      ka0[nf] = *(const bf16x8*)(kb + (nf * 16 + l15) * 64 + l4 * 8);
      ka1[nf] = *(const bf16x8*)(kb + (nf * 16 + l15) * 64 + 32 + l4 * 8);
    }
    float p[4][4];
#pragma unroll
    for (int nf = 0; nf < 4; ++nf) {
      f32x4 z = {0.f, 0.f, 0.f, 0.f};
      z = __builtin_amdgcn_mfma_f32_16x16x32_bf16(ka0[nf], qb0, z, 0, 0, 0);
      z = __builtin_amdgcn_mfma_f32_16x16x32_bf16(ka1[nf], qb1, z, 0, 0, 0);
#pragma unroll
      for (int r = 0; r < 4; ++r) {
        float sc = z[r] * 0.125f;
        if (kt == qt && (nf * 16 + l4 * 4 + r) > (w * 16 + l15)) sc = -INFINITY;
        p[nf][r] = sc;
      }
    }
    // row max: in-register tree + 2 cross-lane
    float m0 = fmaxf(fmaxf(p[0][0], p[0][1]), fmaxf(p[0][2], p[0][3]));
    float m1 = fmaxf(fmaxf(p[1][0], p[1][1]), fmaxf(p[1][2], p[1][3]));
    float m2 = fmaxf(fmaxf(p[2][0], p[2][1]), fmaxf(p[2][2], p[2][3]));
    float m3 = fmaxf(fmaxf(p[3][0], p[3][1]), fmaxf(p[3][2], p[3][3]));
    float mx = fmaxf(fmaxf(m0, m1), fmaxf(m2, m3));
    mx = fmaxf(mx, __shfl_xor(mx, 16));
    mx = fmaxf(mx, __shfl_xor(mx, 32));
    const float mn = fmaxf(mrun, mx);
    const float so = __expf(mrun - mn);
    float rs = 0.f;
#pragma unroll
    for (int nf = 0; nf < 4; ++nf) {
      float e0 = __expf(p[nf][0] - mn), e1 = __expf(p[nf][1] - mn);
      float e2 = __expf(p[nf][2] - mn), e3 = __expf(p[nf][3] - mn);
      p[nf][0] = e0; p[nf][1] = e1; p[nf][2] = e2; p[nf][3] = e3;
      rs += (e0 + e1) + (e2 + e3);
    }
    rs += __shfl_xor(rs, 16);
    rs += __shfl_xor(rs, 32);
    lrun = lrun * so + rs;
    mrun = mn;
    // rescale acc (acc rows indexed by q = l4*4+r -> fetch so from lane l4*4+r)
    float soq[4];
#pragma unroll
    for (int r = 0; r < 4; ++r) soq[r] = __shfl(so, l4 * 4 + r);
#pragma unroll
    for (int df = 0; df < 4; ++df)
#pragma unroll
      for (int r = 0; r < 4; ++r) acc[df][r] *= soq[r];
    // P -> LDS: row q=l15, k-contiguous 4-packs, XOR-swizzled
#pragma unroll
    for (int nf = 0; nf < 4; ++nf) {
      ushort4 pk;
      pk.x = f2bf(p[nf][0]); pk.y = f2bf(p[nf][1]);
      pk.z = f2bf(p[nf][2]); pk.w = f2bf(p[nf][3]);
      *(ushort4*)(myP + ((l15 * 128 + nf * 32 + l4 * 8) ^ swz)) = pk;
    }
    const bf16x8 pa0 = *(const bf16x8*)(myP + ((l15 * 128 + l4 * 16) ^ swz));
    const bf16x8 pa1 = *(const bf16x8*)(myP + ((l15 * 128 + 64 + l4 * 16) ^ swz));
#pragma unroll
    for (int df = 0; df < 4; ++df) {
      acc[df] = __builtin_amdgcn_mfma_f32_16x16x32_bf16(pa0, vf0[df], acc[df], 0, 0, 0);
      acc[df] = __builtin_amdgcn_mfma_f32_16x16x32_bf16(pa1, vf1[df], acc[df], 0, 0, 0);
    }
  }
  const int b = bh >> 4, h = bh & 15;
  float lq[4];
#pragma unroll
  for (int r = 0; r < 4; ++r) lq[r] = __shfl(lrun, l4 * 4 + r);
#pragma unroll
  for (int r = 0; r < 4; ++r) {
    float inv = 1.f / lq[r];
    int qrow = qrow0 + l4 * 4 + r;
#pragma unroll
    for (int df = 0; df < 4; ++df) {
      AO[(size_t)(b * SEQ + qrow) * DM + h * 64 + df * 16 + l15] = f2bf(acc[df][r] * inv);
    }
  }
}

extern "C" void kernel_launch(void* const* d_in, const int* in_sizes, int n_in,
                              void* d_out, int out_size, void* d_ws, size_t ws_size,
                              hipStream_t stream) {
  const float* Q = (const float*)d_in[0];
  const float* K = (const float*)d_in[1];
  const float* V = (const float*)d_in[2];
  const float* wq = (const float*)d_in[3];
  const float* wk = (const float*)d_in[4];
  const float* wv = (const float*)d_in[5];
  const float* wo = (const float*)d_in[6];
  float* out = (float*)d_out;
  char* ws = (char*)d_ws;

  ushort* XQ = (ushort*)(ws + 0);          // 8 MB each
  ushort* XK = (ushort*)(ws + 8388608);
  ushort* XV = (ushort*)(ws + 16777216);
  ushort* WQ = (ushort*)(ws + 25165824);   // 2 MB each
  ushort* WK = (ushort*)(ws + 27262976);
  ushort* WV = (ushort*)(ws + 29360128);
  ushort* WO = (ushort*)(ws + 31457280);
  ushort* YQ = (ushort*)(ws + 33554432);   // 8 MB each
  ushort* YK = (ushort*)(ws + 41943040);
  ushort* YV = (ushort*)(ws + 50331648);
  float* TAB = (float*)(ws + 58720256);    // 512 KB
  // aliases (stream-ordered reuse)
  ushort* qTt = XQ;
  ushort* kTt = XK;
  ushort* vTt = XV;
  ushort* AO = YQ;

  const int NX4 = BATCH * SEQ * DM / 4;
  const int NW4 = DM * DM / 4;
  k_cast<<<2048, 256, 0, stream>>>(Q, XQ, NX4);
  k_cast<<<2048, 256, 0, stream>>>(K, XK, NX4);
  k_cast<<<2048, 256, 0, stream>>>(V, XV, NX4);
  k_cast<<<1024, 256, 0, stream>>>(wq, WQ, NW4);
  k_cast<<<1024, 256, 0, stream>>>(wk, WK, NW4);
  k_cast<<<1024, 256, 0, stream>>>(wv, WV, NW4);
  k_cast<<<1024, 256, 0, stream>>>(wo, WO, NW4);
  k_rope_tab<<<(SEQ * 32) / 256, 256, 0, stream>>>(TAB);

  dim3 gg(DM / 128, (BATCH * SEQ) / 128);
  k_gemm_bt<ushort><<<gg, 256, 0, stream>>>(XQ, WQ, YQ, BATCH * SEQ, DM, DM);
  k_gemm_bt<ushort><<<gg, 256, 0, stream>>>(XK, WK, YK, BATCH * SEQ, DM, DM);
  k_gemm_bt<ushort><<<gg, 256, 0, stream>>>(XV, WV, YV, BATCH * SEQ, DM, DM);

  k_rope<<<(BH * SEQ * 32) / 256, 256, 0, stream>>>(YQ, qTt, TAB);
  k_rope<<<(BH * SEQ * 32) / 256, 256, 0, stream>>>(YK, kTt, TAB);
  k_tr_v<<<dim3(SEQ / 64, BH), 256, 0, stream>>>(YV, vTt);

  k_flash<<<dim3(BH, SEQ / 64), 256, 0, stream>>>(qTt, kTt, vTt, AO);

  k_gemm_bt<float><<<gg, 256, 0, stream>>>(AO, WO, out, BATCH * SEQ, DM, DM);
}

// Round 3
// 236.301 us; speedup vs baseline: 1.7747x; 1.2588x over previous
//
#include <hip/hip_runtime.h>

#define SEQ 2048
#define BATCH 2
#define DM 1024
#define NH 16
#define DK 64
#define BH (BATCH*NH)

typedef __attribute__((ext_vector_type(8))) short bf16x8;
typedef __attribute__((ext_vector_type(4))) float f32x4;

__device__ __forceinline__ ushort f2bf(float f) {
  union { float f; unsigned u; } v; v.f = f;
  unsigned r = (v.u + 0x7fffu + ((v.u >> 16) & 1u)) >> 16;
  return (ushort)r;
}
__device__ __forceinline__ float bf2f(ushort h) {
  union { unsigned u; float f; } v; v.u = ((unsigned)h) << 16;
  return v.f;
}

// ---------------- batched cast fp32 -> bf16 (z = tensor index) ----------------
struct P4 { const float* p0; const float* p1; const float* p2; const float* p3; };
__global__ void k_castN(P4 in, ushort* __restrict__ out, int n4) {
  const float* src = (blockIdx.z == 0) ? in.p0 : (blockIdx.z == 1) ? in.p1
                    : (blockIdx.z == 2) ? in.p2 : in.p3;
  ushort* dst = out + (size_t)blockIdx.z * (size_t)n4 * 4;
  int i = blockIdx.x * blockDim.x + threadIdx.x;
  int st = gridDim.x * blockDim.x;
  for (; i < n4; i += st) {
    float4 v = reinterpret_cast<const float4*>(src)[i];
    ushort4 o;
    o.x = f2bf(v.x); o.y = f2bf(v.y); o.z = f2bf(v.z); o.w = f2bf(v.w);
    reinterpret_cast<ushort4*>(dst)[i] = o;
  }
}

// ---------------- RoPE cos/sin table: [SEQ][32] pairs ----------------
__global__ void k_rope_tab(float* __restrict__ tab) {
  int id = blockIdx.x * blockDim.x + threadIdx.x;
  if (id >= SEQ * 32) return;
  int s = id >> 5, i = id & 31;
  float inv = powf(10000.f, -(float)i / 32.f);
  float ang = (float)s * inv;
  float sn, cs;
  sincosf(ang, &sn, &cs);
  tab[id * 2] = cs;
  tab[id * 2 + 1] = sn;
}

// ---------------- RoPE apply + head-transpose: Y[b,s,h*64+d] -> T[bh,s,d] ----------------
// scale folds softmax 1/sqrt(dk) * log2(e) into Q (fp32, pre-quantization)
__global__ void k_rope(const ushort* __restrict__ Y, ushort* __restrict__ T,
                       const float* __restrict__ tab, float scale) {
  int idx = blockIdx.x * blockDim.x + threadIdx.x;
  if (idx >= BH * SEQ * 32) return;
  int i = idx & 31;
  int s = (idx >> 5) & (SEQ - 1);
  int bh = idx >> 16;            // SEQ*32 == 1<<16
  int b = bh >> 4, h = bh & 15;
  ushort2 x = *(const ushort2*)(Y + (size_t)(b * SEQ + s) * DM + h * 64 + 2 * i);
  float xe = bf2f(x.x), xo = bf2f(x.y);
  float cs = tab[((s << 5) + i) * 2], sn = tab[((s << 5) + i) * 2 + 1];
  ushort2 o;
  o.x = f2bf((xe * cs - xo * sn) * scale);
  o.y = f2bf((xe * sn + xo * cs) * scale);
  *(ushort2*)(T + (size_t)(bh * SEQ + s) * 64 + 2 * i) = o;
}

// ---------------- V transpose: Y[b,s,h*64+d] -> VT[bh, d, s] ----------------
__global__ __launch_bounds__(256) void k_tr_v(const ushort* __restrict__ Y,
                                              ushort* __restrict__ VT) {
  __shared__ ushort tile[64][65];
  const int st = blockIdx.x, bh = blockIdx.y;
  const int b = bh >> 4, h = bh & 15;
  const int d = threadIdx.x & 63, s4 = threadIdx.x >> 6;
#pragma unroll
  for (int p = 0; p < 16; ++p) {
    int sl = p * 4 + s4;
    tile[d][sl] = Y[(size_t)(b * SEQ + st * 64 + sl) * DM + h * 64 + d];
  }
  __syncthreads();
  const int sl = threadIdx.x & 63, d4 = threadIdx.x >> 6;
#pragma unroll
  for (int p = 0; p < 16; ++p) {
    int dl = p * 4 + d4;
    VT[(size_t)bh * DK * SEQ + (size_t)dl * SEQ + st * 64 + sl] = tile[dl][sl];
  }
}

// ---------------- async global->LDS 16B ----------------
__device__ __forceinline__ void gll16(const void* g, void* l) {
  __builtin_amdgcn_global_load_lds((const __attribute__((address_space(1))) void*)g,
                                   (__attribute__((address_space(3))) void*)l, 16, 0, 0);
}

// ---------------- GEMM: C[M,N] = A[M,K] * Bw[N,K]^T  (bf16 in, OUT out) ----------------
// blockIdx.z batches independent (A, Bw, C) triples (contiguous in memory).
template <typename OUT>
__global__ __launch_bounds__(256) void k_gemm_bt(const ushort* __restrict__ A,
                                                 const ushort* __restrict__ Bw,
                                                 OUT* __restrict__ C, int M, int N, int K) {
  A += (size_t)blockIdx.z * ((size_t)M * K);
  Bw += (size_t)blockIdx.z * ((size_t)N * K);
  C += (size_t)blockIdx.z * ((size_t)M * N);
  __shared__ ushort As[128 * 32];
  __shared__ ushort Bs[128 * 32];
  const int tid = threadIdx.x;
  const int w = tid >> 6, lane = tid & 63;
  const int l15 = lane & 15, l4 = lane >> 4;
  const int m0 = blockIdx.y * 128, n0 = blockIdx.x * 128;
  const int wr = w >> 1, wc = w & 1;
  const int lrow = lane >> 2, lcol = (lane & 3) * 8;
  f32x4 acc[4][4] = {};
  for (int kk = 0; kk < K; kk += 32) {
    __syncthreads();
    gll16(A + (size_t)(m0 + w * 16 + lrow) * K + kk + lcol, (void*)(As + w * 512));
    gll16(A + (size_t)(m0 + 64 + w * 16 + lrow) * K + kk + lcol, (void*)(As + 2048 + w * 512));
    gll16(Bw + (size_t)(n0 + w * 16 + lrow) * K + kk + lcol, (void*)(Bs + w * 512));
    gll16(Bw + (size_t)(n0 + 64 + w * 16 + lrow) * K + kk + lcol, (void*)(Bs + 2048 + w * 512));
    __syncthreads();
    bf16x8 af[4], bfr[4];
#pragma unroll
    for (int i = 0; i < 4; ++i)
      af[i] = *(const bf16x8*)(As + (wr * 64 + i * 16 + l15) * 32 + l4 * 8);
#pragma unroll
    for (int i = 0; i < 4; ++i)
      bfr[i] = *(const bf16x8*)(Bs + (wc * 64 + i * 16 + l15) * 32 + l4 * 8);
#pragma unroll
    for (int mi = 0; mi < 4; ++mi)
#pragma unroll
      for (int ni = 0; ni < 4; ++ni)
        acc[mi][ni] = __builtin_amdgcn_mfma_f32_16x16x32_bf16(af[mi], bfr[ni], acc[mi][ni], 0, 0, 0);
  }
#pragma unroll
  for (int mi = 0; mi < 4; ++mi)
#pragma unroll
    for (int ni = 0; ni < 4; ++ni)
#pragma unroll
      for (int r = 0; r < 4; ++r) {
        int row = m0 + wr * 64 + mi * 16 + l4 * 4 + r;
        int col = n0 + wc * 64 + ni * 16 + l15;
        float v = acc[mi][ni][r];
        if constexpr (sizeof(OUT) == 2)
          C[(size_t)row * N + col] = (OUT)f2bf(v);
        else
          C[(size_t)row * N + col] = (OUT)v;
      }
}

// ---------------- causal flash attention (swapped-QK^T, K-pipelined) ----------------
// qT (pre-scaled by 0.125*log2e), kT: [bh, s, 64]   vT: [bh, 64, s]   AO: [b, s, h*64+d]
// Per wave: 16 q-rows. S^T = mfma(K,Q). exp2-domain softmax. K fragments
// double-buffered in regs: K(kt+1) issued right after QK(kt) -> latency hidden
// under softmax + P-LDS + PV. Diagonal tile peeled (mask only there).
#define LOADK(KB, kt_) do {                                                    \
    const ushort* kb_ = kT + hb + (size_t)(kt_) * 64 * 64;                     \
    _Pragma("unroll")                                                          \
    for (int nf = 0; nf < 4; ++nf) {                                           \
      KB##0[nf] = *(const bf16x8*)(kb_ + (nf * 16 + l15) * 64 + l4 * 8);       \
      KB##1[nf] = *(const bf16x8*)(kb_ + (nf * 16 + l15) * 64 + 32 + l4 * 8);  \
    }                                                                          \
  } while (0)

#define STEP(KC, KN, kt_, DIAG, PREF) do {                                     \
    const ushort* vb_ = vT + vbase + (size_t)(kt_) * 64;                       \
    bf16x8 vf0[4], vf1[4];                                                     \
    _Pragma("unroll")                                                          \
    for (int df = 0; df < 4; ++df) {                                           \
      vf0[df] = *(const bf16x8*)(vb_ + (size_t)(df * 16 + l15) * SEQ + l4 * 8);\
      vf1[df] = *(const bf16x8*)(vb_ + (size_t)(df * 16 + l15) * SEQ + 32 + l4 * 8);\
    }                                                                          \
    float p[4][4];                                                             \
    _Pragma("unroll")                                                          \
    for (int nf = 0; nf < 4; ++nf) {                                           \
      f32x4 z = {0.f, 0.f, 0.f, 0.f};                                          \
      z = __builtin_amdgcn_mfma_f32_16x16x32_bf16(KC##0[nf], qb0, z, 0, 0, 0); \
      z = __builtin_amdgcn_mfma_f32_16x16x32_bf16(KC##1[nf], qb1, z, 0, 0, 0); \
      _Pragma("unroll")                                                        \
      for (int r = 0; r < 4; ++r) {                                            \
        float sc = z[r];                                                       \
        if (DIAG && (nf * 16 + l4 * 4 + r) > (w * 16 + l15)) sc = -INFINITY;   \
        p[nf][r] = sc;                                                         \
      }                                                                        \
    }                                                                          \
    if (PREF) { LOADK(KN, (kt_) + 1); }                                        \
    float m0_ = fmaxf(fmaxf(p[0][0], p[0][1]), fmaxf(p[0][2], p[0][3]));       \
    float m1_ = fmaxf(fmaxf(p[1][0], p[1][1]), fmaxf(p[1][2], p[1][3]));       \
    float m2_ = fmaxf(fmaxf(p[2][0], p[2][1]), fmaxf(p[2][2], p[2][3]));       \
    float m3_ = fmaxf(fmaxf(p[3][0], p[3][1]), fmaxf(p[3][2], p[3][3]));       \
    float mx = fmaxf(fmaxf(m0_, m1_), fmaxf(m2_, m3_));                        \
    mx = fmaxf(mx, __shfl_xor(mx, 16));                                        \
    mx = fmaxf(mx, __shfl_xor(mx, 32));                                        \
    const float mn = fmaxf(mrun, mx);                                          \
    const float so = __builtin_amdgcn_exp2f(mrun - mn);                        \
    float rs = 0.f;                                                            \
    _Pragma("unroll")                                                          \
    for (int nf = 0; nf < 4; ++nf) {                                           \
      float e0 = __builtin_amdgcn_exp2f(p[nf][0] - mn);                        \
      float e1 = __builtin_amdgcn_exp2f(p[nf][1] - mn);                        \
      float e2 = __builtin_amdgcn_exp2f(p[nf][2] - mn);                        \
      float e3 = __builtin_amdgcn_exp2f(p[nf][3] - mn);                        \
      p[nf][0] = e0; p[nf][1] = e1; p[nf][2] = e2; p[nf][3] = e3;              \
      rs += (e0 + e1) + (e2 + e3);                                             \
    }                                                                          \
    rs += __shfl_xor(rs, 16);                                                  \
    rs += __shfl_xor(rs, 32);                                                  \
    lrun = lrun * so + rs;                                                     \
    mrun = mn;                                                                 \
    float soq[4];                                                              \
    _Pragma("unroll")                                                          \
    for (int r = 0; r < 4; ++r) soq[r] = __shfl(so, l4 * 4 + r);               \
    _Pragma("unroll")                                                          \
    for (int df = 0; df < 4; ++df)                                             \
      _Pragma("unroll")                                                        \
      for (int r = 0; r < 4; ++r) acc[df][r] *= soq[r];                        \
    _Pragma("unroll")                                                          \
    for (int nf = 0; nf < 4; ++nf) {                                           \
      ushort4 pk;                                                              \
      pk.x = f2bf(p[nf][0]); pk.y = f2bf(p[nf][1]);                            \
      pk.z = f2bf(p[nf][2]); pk.w = f2bf(p[nf][3]);                            \
      *(ushort4*)(myP + ((l15 * 128 + nf * 32 + l4 * 8) ^ swz)) = pk;          \
    }                                                                          \
    const bf16x8 pa0 = *(const bf16x8*)(myP + ((l15 * 128 + l4 * 16) ^ swz));  \
    const bf16x8 pa1 = *(const bf16x8*)(myP + ((l15 * 128 + 64 + l4 * 16) ^ swz));\
    _Pragma("unroll")                                                          \
    for (int df = 0; df < 4; ++df) {                                           \
      acc[df] = __builtin_amdgcn_mfma_f32_16x16x32_bf16(pa0, vf0[df], acc[df], 0, 0, 0);\
      acc[df] = __builtin_amdgcn_mfma_f32_16x16x32_bf16(pa1, vf1[df], acc[df], 0, 0, 0);\
    }                                                                          \
  } while (0)

__global__ __launch_bounds__(256, 3) void k_flash(const ushort* __restrict__ qT,
                                                  const ushort* __restrict__ kT,
                                                  const ushort* __restrict__ vT,
                                                  ushort* __restrict__ AO) {
  __shared__ char Plds[4 * 2048];
  const int bh = blockIdx.x;
  const int qt = (SEQ / 64 - 1) - blockIdx.y;   // longest blocks dispatch first
  const int tid = threadIdx.x, w = tid >> 6, lane = tid & 63;
  const int l15 = lane & 15, l4 = lane >> 4;
  const size_t hb = (size_t)bh * SEQ * DK;
  const size_t vbase = (size_t)bh * DK * SEQ;
  const int qrow0 = qt * 64 + w * 16;
  const bf16x8 qb0 = *(const bf16x8*)(qT + hb + (size_t)(qrow0 + l15) * 64 + l4 * 8);
  const bf16x8 qb1 = *(const bf16x8*)(qT + hb + (size_t)(qrow0 + l15) * 64 + 32 + l4 * 8);
  f32x4 acc[4] = {};
  float mrun = -INFINITY, lrun = 0.f;
  char* myP = (char*)Plds + w * 2048;
  const int swz = (l15 & 7) << 4;
  bf16x8 kA0[4], kA1[4], kB0[4], kB1[4];
  LOADK(kA, 0);
  int kt = 0;
  for (; kt + 1 < qt; kt += 2) {
    STEP(kA, kB, kt, false, true);
    STEP(kB, kA, kt + 1, false, true);
  }
  if (kt < qt) {
    STEP(kA, kB, kt, false, true);
    STEP(kB, kA, qt, true, false);
  } else {
    STEP(kA, kB, qt, true, false);
  }
  const int b = bh >> 4, h = bh & 15;
  float lq[4];
#pragma unroll
  for (int r = 0; r < 4; ++r) lq[r] = __shfl(lrun, l4 * 4 + r);
#pragma unroll
  for (int r = 0; r < 4; ++r) {
    float inv = 1.f / lq[r];
    int qrow = qrow0 + l4 * 4 + r;
#pragma unroll
    for (int df = 0; df < 4; ++df) {
      AO[(size_t)(b * SEQ + qrow) * DM + h * 64 + df * 16 + l15] = f2bf(acc[df][r] * inv);
    }
  }
}

extern "C" void kernel_launch(void* const* d_in, const int* in_sizes, int n_in,
                              void* d_out, int out_size, void* d_ws, size_t ws_size,
                              hipStream_t stream) {
  const float* Q = (const float*)d_in[0];
  const float* K = (const float*)d_in[1];
  const float* V = (const float*)d_in[2];
  const float* wq = (const float*)d_in[3];
  const float* wk = (const float*)d_in[4];
  const float* wv = (const float*)d_in[5];
  const float* wo = (const float*)d_in[6];
  float* out = (float*)d_out;
  char* ws = (char*)d_ws;

  ushort* XQ = (ushort*)(ws + 0);          // 8 MB each (XQ,XK,XV contiguous)
  ushort* WQ = (ushort*)(ws + 25165824);   // 2 MB each (WQ,WK,WV,WO contiguous)
  ushort* YQ = (ushort*)(ws + 33554432);   // 8 MB each (YQ,YK,YV contiguous)
  ushort* YK = (ushort*)(ws + 41943040);
  ushort* YV = (ushort*)(ws + 50331648);
  float* TAB = (float*)(ws + 58720256);    // 512 KB
  // aliases (stream-ordered reuse)
  ushort* qTt = XQ;
  ushort* kTt = (ushort*)(ws + 8388608);
  ushort* vTt = (ushort*)(ws + 16777216);
  ushort* AO = YQ;

  const int NX4 = BATCH * SEQ * DM / 4;
  const int NW4 = DM * DM / 4;
  P4 xin = {Q, K, V, nullptr};
  P4 win = {wq, wk, wv, wo};
  k_castN<<<dim3(1024, 1, 3), 256, 0, stream>>>(xin, XQ, NX4);
  k_castN<<<dim3(1024, 1, 4), 256, 0, stream>>>(win, WQ, NW4);
  k_rope_tab<<<(SEQ * 32) / 256, 256, 0, stream>>>(TAB);

  // QKV projections in one dispatch (grid.z = 3 -> 768 blocks, 3 blocks/CU)
  k_gemm_bt<ushort><<<dim3(DM / 128, (BATCH * SEQ) / 128, 3), 256, 0, stream>>>(
      XQ, WQ, YQ, BATCH * SEQ, DM, DM);

  const float QSCALE = 0.125f * 1.4426950408889634f;  // 1/sqrt(dk) * log2(e)
  k_rope<<<(BH * SEQ * 32) / 256, 256, 0, stream>>>(YQ, qTt, TAB, QSCALE);
  k_rope<<<(BH * SEQ * 32) / 256, 256, 0, stream>>>(YK, kTt, TAB, 1.0f);
  k_tr_v<<<dim3(SEQ / 64, BH), 256, 0, stream>>>(YV, vTt);

  k_flash<<<dim3(BH, SEQ / 64), 256, 0, stream>>>(qTt, kTt, vTt, AO);

  k_gemm_bt<float><<<dim3(DM / 128, (BATCH * SEQ) / 128, 1), 256, 0, stream>>>(
      AO, WQ + 3 * DM * DM, out, BATCH * SEQ, DM, DM);
}